// Round 1
// baseline (227.254 us; speedup 1.0000x reference)
//
#include <hip/hip_runtime.h>
#include <hip/hip_bf16.h>

#define NB 32768
#define NPG 15
#define GPB 8
#define THREADS 256
#define BIAS_SP 0.5413248546129181f

typedef __attribute__((ext_vector_type(8))) short bf16x8;
typedef __attribute__((ext_vector_type(4))) float f32x4;

static __device__ __forceinline__ unsigned short f2bf(float f) {
    union { float f; unsigned u; } v; v.f = f;
    unsigned r = v.u + 0x7FFFu + ((v.u >> 16) & 1u);
    return (unsigned short)(r >> 16);
}
static __device__ __forceinline__ float bf2f(unsigned short s) {
    union { unsigned u; float f; } v; v.u = ((unsigned)s) << 16;
    return v.f;
}
static __device__ __forceinline__ float fast_tanh(float xx) {
    float a = __builtin_fabsf(xx);
    float e = __expf(-2.0f * a);
    float t = __fdividef(1.0f - e, 1.0f + e);
    return __builtin_copysignf(t, xx);
}

// LDS tile per graph: 16 rows x 128 bf16 cols = 16 rows x 16 slots(16B) = 4096 B.
// Swizzle: 16B-slot index ^= (row & 7) within each half (h: slots 0-7, agg: 8-15).

__global__ __launch_bounds__(THREADS) void leg_actor_kernel(
    const float* __restrict__ x,
    const float* __restrict__ Wt, const float* __restrict__ bt,
    const float* __restrict__ Wl, const float* __restrict__ bl,
    const float* __restrict__ Wroot, const float* __restrict__ Wrel,
    const float* __restrict__ gcb,
    const float* __restrict__ legW, const float* __restrict__ legB,
    const float* __restrict__ torW, const float* __restrict__ torB,
    float* __restrict__ out)
{
    __shared__ __align__(16) unsigned char smem[GPB * 4096];
    const int tid  = threadIdx.x;
    const int lane = tid & 63;
    const int w    = tid >> 6;          // wave id = N-tile (16 output cols)
    const int g0   = blockIdx.x * GPB;

    // read one bf16 h element (col c = lane, 0..63) at (g,row)
    auto RD = [&](int g, int row) -> float {
        const int slot = ((lane >> 3) ^ row) & 7;
        return bf2f(*(const unsigned short*)(smem + g * 4096 + row * 256 + slot * 16 + (lane & 7) * 2));
    };
    // neighbor aggregation: agg[n][c] written to cols 64..127
    auto do_agg = [&]() {
        for (int q = w; q < GPB * NPG; q += 4) {
            const int g = q / NPG;
            const int n = q - g * NPG;
            const int b3 = (n / 3) * 3;
            float s;
            if (n == b3) {                       // torso: legs + adjacent torsos
                s = RD(g, b3 + 1) + RD(g, b3 + 2);
                if (b3 > 0)  s += RD(g, b3 - 3);
                if (b3 < 12) s += RD(g, b3 + 3);
            } else {                             // leg: its torso
                s = RD(g, b3);
            }
            const int slot = 8 | (((lane >> 3) ^ n) & 7);
            *(unsigned short*)(smem + g * 4096 + n * 256 + slot * 16 + (lane & 7) * 2) = f2bf(s);
        }
    };

    // ---------- B fragments (weights) for the 3 GraphConv layers ----------
    // Wcat = [Wroot; Wrel] (128x64). B frag (32x16) per kstep s: lane holds
    // k = s*32 + (lane>>4)*8 + j, col = w*16 + (lane&15).
    const int bcol = (w << 4) + (lane & 15);
    bf16x8 bfr[3][4];
    float cb[3];
    #pragma unroll
    for (int i = 0; i < 3; ++i) {
        cb[i] = gcb[i * 64 + bcol];
        #pragma unroll
        for (int s = 0; s < 4; ++s) {
            const float* M = (s < 2) ? Wroot : Wrel;
            const int kb = ((s & 1) << 5) + ((lane >> 4) << 3);
            bf16x8 f;
            #pragma unroll
            for (int j = 0; j < 8; ++j)
                f[j] = (short)f2bf(M[i * 4096 + (kb + j) * 64 + bcol]);
            bfr[i][s] = f;
        }
    }

    // ---------- encoder weights (this thread's output column = lane) ----------
    float ewt[8], ewl[4];
    #pragma unroll
    for (int k = 0; k < 8; ++k) ewt[k] = Wt[k * 64 + lane];
    #pragma unroll
    for (int k = 0; k < 4; ++k) ewl[k] = Wl[k * 64 + lane];
    const float ebt = bt[lane], ebl = bl[lane];

    // ---------- encoder: h0 = tanh(x @ W + b), torso vs leg ----------
    #pragma unroll
    for (int pp = 0; pp < 4; ++pp) {
        const int p = w + (pp << 2);            // wave w handles rows w, w+4, w+8, w+12
        if (p < NPG) {
            const bool isT = (p % 3) == 0;
            #pragma unroll
            for (int g = 0; g < GPB; ++g) {
                const float* xr = x + ((size_t)(g0 + g) * NPG + p) * 8;
                const float4 x0 = *(const float4*)xr;
                float acc;
                if (isT) {
                    const float4 x1 = *(const float4*)(xr + 4);
                    acc = ebt + x0.x*ewt[0] + x0.y*ewt[1] + x0.z*ewt[2] + x0.w*ewt[3]
                              + x1.x*ewt[4] + x1.y*ewt[5] + x1.z*ewt[6] + x1.w*ewt[7];
                } else {
                    acc = ebl + x0.x*ewl[0] + x0.y*ewl[1] + x0.z*ewl[2] + x0.w*ewl[3];
                }
                const float h = fast_tanh(acc);
                const int slot = ((lane >> 3) ^ p) & 7;
                *(unsigned short*)(smem + g * 4096 + p * 256 + slot * 16 + (lane & 7) * 2) = f2bf(h);
            }
        }
    }
    __syncthreads();
    do_agg();
    __syncthreads();

    // ---------- 3x GraphConv via MFMA ----------
    #pragma unroll
    for (int it = 0; it < 3; ++it) {
        f32x4 cacc[GPB];
        #pragma unroll
        for (int g = 0; g < GPB; ++g) {
            f32x4 a = { cb[it], cb[it], cb[it], cb[it] };
            #pragma unroll
            for (int s = 0; s < 4; ++s) {
                // A frag: row = lane&15, 8 bf16 at cols s*32 + (lane>>4)*8 ..
                const int row  = lane & 15;
                const int slot = (s << 2) + (lane >> 4);
                const int sw   = (slot & 8) | ((slot ^ row) & 7);
                const bf16x8 af = *(const bf16x8*)(smem + g * 4096 + row * 256 + sw * 16);
                a = __builtin_amdgcn_mfma_f32_16x16x32_bf16(af, bfr[it][s], a, 0, 0, 0);
            }
            cacc[g] = a;
        }
        __syncthreads();    // all A reads done before overwriting h
        #pragma unroll
        for (int g = 0; g < GPB; ++g) {
            #pragma unroll
            for (int r = 0; r < 4; ++r) {
                const int row = ((lane >> 4) << 2) + r;     // C/D: row=(lane>>4)*4+reg
                const int col = (w << 4) + (lane & 15);     //      col=lane&15 (+tile)
                const float h = fast_tanh(cacc[g][r]);
                const int sw = ((col >> 3) ^ row) & 7;
                *(unsigned short*)(smem + g * 4096 + row * 256 + sw * 16 + (col & 7) * 2) = f2bf(h);
            }
        }
        __syncthreads();
        if (it < 2) {
            do_agg();
            __syncthreads();
        }
    }

    // ---------- heads: out[p-1][j] = h[p] . W[:,j] + b ----------
    if (tid < 224) {
        const int m  = tid % 56;        // (p,j) combo
        const int gh = tid / 56;        // handles graphs gh*2, gh*2+1
        const int p  = (m >> 2) + 1;
        const int j  = m & 3;
        const float* Wc; float bias;
        if (p % 3 == 0) {
            const int ti = p / 3 - 1;
            Wc = torW + ti * 256 + j;
            bias = torB[ti * 4 + j];
        } else {
            const int li = 2 * (p / 3) + (p % 3) - 1;
            Wc = legW + li * 256 + j;
            bias = legB[li * 4 + j];
        }
        const int ga = gh * 2, gb = ga + 1;
        float acc0 = bias, acc1 = bias;
        #pragma unroll
        for (int k8 = 0; k8 < 8; ++k8) {
            const int sw = (k8 ^ p) & 7;
            const bf16x8 h0v = *(const bf16x8*)(smem + ga * 4096 + p * 256 + sw * 16);
            const bf16x8 h1v = *(const bf16x8*)(smem + gb * 4096 + p * 256 + sw * 16);
            #pragma unroll
            for (int jj = 0; jj < 8; ++jj) {
                const float wv = Wc[(k8 * 8 + jj) * 4];
                acc0 += bf2f((unsigned short)h0v[jj]) * wv;
                acc1 += bf2f((unsigned short)h1v[jj]) * wv;
            }
        }
        // blocks[14][4] -> [28][2]: loc = j even, scale = j odd
        const int mloc = ((p - 1) << 1) + (j >> 1);
        const size_t ia = (size_t)(g0 + ga) * 28 + mloc;
        const size_t ib = (size_t)(g0 + gb) * 28 + mloc;
        if ((j & 1) == 0) {
            out[ia] = acc0;
            out[ib] = acc1;
        } else {
            float z0 = acc0 + BIAS_SP;
            float z1 = acc1 + BIAS_SP;
            float sp0 = z0 > 15.f ? z0 : __logf(1.f + __expf(z0));
            float sp1 = z1 > 15.f ? z1 : __logf(1.f + __expf(z1));
            out[(size_t)NB * 28 + ia] = fmaxf(sp0, 1e-4f);
            out[(size_t)NB * 28 + ib] = fmaxf(sp1, 1e-4f);
        }
    }
}

extern "C" void kernel_launch(void* const* d_in, const int* in_sizes, int n_in,
                              void* d_out, int out_size, void* d_ws, size_t ws_size,
                              hipStream_t stream) {
    (void)in_sizes; (void)n_in; (void)out_size; (void)d_ws; (void)ws_size;
    const float* x     = (const float*)d_in[0];
    // d_in[1] = edge_index (fixed template, unused), d_in[2] = batch_size (32768)
    const float* Wt    = (const float*)d_in[3];
    const float* bt    = (const float*)d_in[4];
    const float* Wl    = (const float*)d_in[5];
    const float* bl    = (const float*)d_in[6];
    const float* Wroot = (const float*)d_in[7];
    const float* Wrel  = (const float*)d_in[8];
    const float* gcb   = (const float*)d_in[9];
    const float* legW  = (const float*)d_in[10];
    const float* legB  = (const float*)d_in[11];
    const float* torW  = (const float*)d_in[12];
    const float* torB  = (const float*)d_in[13];
    leg_actor_kernel<<<NB / GPB, THREADS, 0, stream>>>(
        x, Wt, bt, Wl, bl, Wroot, Wrel, gcb, legW, legB, torW, torB, (float*)d_out);
}

// Round 2
// 82.959 us; speedup vs baseline: 2.7393x; 2.7393x over previous
//
#include <hip/hip_runtime.h>

#define NB 32768
#define GPB 4
#define THREADS 256
#define BIAS_SP 0.5413248546129181f

typedef __attribute__((ext_vector_type(8))) short bf16x8;
typedef __attribute__((ext_vector_type(4))) float f32x4;
typedef __attribute__((ext_vector_type(4))) unsigned int u32x4;

static __device__ __forceinline__ unsigned f2bfu(float f) {
    union { float f; unsigned u; } v; v.f = f;
    return (v.u + 0x8000u) >> 16;
}
static __device__ __forceinline__ float bf2f(unsigned short s) {
    union { unsigned u; float f; } v; v.u = ((unsigned)s) << 16;
    return v.f;
}
static __device__ __forceinline__ float lof(unsigned u) {
    union { unsigned u; float f; } v; v.u = u << 16; return v.f;
}
static __device__ __forceinline__ float hif(unsigned u) {
    union { unsigned u; float f; } v; v.u = u & 0xFFFF0000u; return v.f;
}
static __device__ __forceinline__ float fast_tanh(float xx) {
    float e = __expf(2.0f * xx);                       // inf -> t=1, 0 -> t=-1: both correct
    return 1.0f - 2.0f * __builtin_amdgcn_rcpf(e + 1.0f);
}

// ---------------------------------------------------------------------------
// Setup: pack conv B-fragments (bf16, MFMA lane order) and head weights
// (bf16 [item=(p-1)*4+j][k=0..63]) into the workspace.
// ws layout (dwords): [0,12288) conv B-frags, [12288,14080) head weights.
// ---------------------------------------------------------------------------
__global__ void setup_kernel(const float* __restrict__ Wroot, const float* __restrict__ Wrel,
                             const float* __restrict__ legW, const float* __restrict__ torW,
                             unsigned* __restrict__ wsw) {
    const int t = blockIdx.x * 256 + threadIdx.x;
    if (t < 3072) {                       // (i,s,ct,lane) B-fragment element pack
        const int i = t >> 10, rem = t & 1023, s = rem >> 8, tt = rem & 255;
        const int lane = tt & 63, ctl = tt >> 6;
        const int bcol = (ctl << 4) + (lane & 15);
        const int kb = ((s & 1) << 5) + ((lane >> 4) << 3);
        const float* M = ((s < 2) ? Wroot : Wrel) + i * 4096 + kb * 64 + bcol;
        u32x4 d;
        #pragma unroll
        for (int dd = 0; dd < 4; ++dd)
            d[dd] = f2bfu(M[(2 * dd) * 64]) | (f2bfu(M[(2 * dd + 1) * 64]) << 16);
        *(u32x4*)(wsw + t * 4) = d;
    } else if (t < 3520) {                // head weights
        const int t2 = t - 3072, item = t2 >> 3, k8 = t2 & 7;
        const int p = (item >> 2) + 1, j = item & 3;
        const int p3 = (p * 11) >> 5;     // p/3 for p<16
        const int pm3 = p - p3 * 3;
        const float* src;
        if (pm3 == 0) src = torW + (p3 - 1) * 256 + j;
        else          src = legW + (2 * p3 + pm3 - 1) * 256 + j;
        u32x4 d;
        #pragma unroll
        for (int dd = 0; dd < 4; ++dd) {
            const int k = (k8 << 3) + 2 * dd;
            d[dd] = f2bfu(src[k * 4]) | (f2bfu(src[(k + 1) * 4]) << 16);
        }
        *(u32x4*)(wsw + 12288 + t2 * 4) = d;
    }
}

// ---------------------------------------------------------------------------
// Main kernel: 4 graphs/block, 4 waves. Wave w = graph w for encoder/agg/heads,
// col-tile w (16 cols) for the MFMA conv layers.
// LDS per graph: 16 rows x 16 slots(16B) = 4KB; slots 0-7 = h, 8-15 = agg.
// Swizzle: slot_low ^= (row & 7) -> all row-strided accesses ~2-way (free).
// ---------------------------------------------------------------------------
#define RDH(r) bf2f(*(const unsigned short*)(smem + wbase + (r) * 256 + (colb ^ (((r) & 7) << 4))))
#define WRA(r, v) *(unsigned short*)(smem + wbase + (r) * 256 + 128 + (colb ^ (((r) & 7) << 4))) = (unsigned short)f2bfu(v)
#define AGG() do { \
    float s0  = RDH(1)  + RDH(2)  + RDH(3); \
    float s3  = RDH(4)  + RDH(5)  + RDH(0) + RDH(6); \
    float s6  = RDH(7)  + RDH(8)  + RDH(3) + RDH(9); \
    float s9  = RDH(10) + RDH(11) + RDH(6) + RDH(12); \
    float s12 = RDH(13) + RDH(14) + RDH(9); \
    WRA(0, s0); WRA(3, s3); WRA(6, s6); WRA(9, s9); WRA(12, s12); \
} while (0)

__global__ __launch_bounds__(THREADS, 4) void leg_main(
    const float* __restrict__ x,
    const float* __restrict__ Wt, const float* __restrict__ bt,
    const float* __restrict__ Wl, const float* __restrict__ bl,
    const float* __restrict__ gcb,
    const float* __restrict__ legB, const float* __restrict__ torB,
    const unsigned* __restrict__ wsw,
    float* __restrict__ out)
{
    __shared__ __align__(16) unsigned char smem[GPB * 4096];
    const int tid  = threadIdx.x;
    const int lane = tid & 63;
    const int ct   = tid >> 6;                 // wave id
    const int g0   = blockIdx.x * GPB;
    const int wbase = ct * 4096;               // this wave's graph tile (enc/agg/heads)

    // --- conv B fragments: 12 coalesced 16B loads from packed ws ---
    bf16x8 bfr[3][4];
    #pragma unroll
    for (int i = 0; i < 3; ++i)
        #pragma unroll
        for (int s = 0; s < 4; ++s)
            bfr[i][s] = *(const bf16x8*)(wsw + ((i * 4 + s) * 256 + tid) * 4);
    const int bcol = (ct << 4) + (lane & 15);
    const float cb0 = gcb[bcol], cb1 = gcb[64 + bcol], cb2 = gcb[128 + bcol];

    // --- precomputed per-lane LDS byte offsets ---
    const int colb = ((lane >> 3) << 4) + ((lane & 7) << 1);   // col = lane (u16 access)
    const int row = lane & 15, kg = lane >> 4;
    const int row3 = (row * 11) >> 5;          // row/3 for row<16
    const int tors = row3 * 3;
    const int isT  = (row == tors);
    const int rowR = isT ? row : tors;         // leg rows remap agg-read to torso h row
    const int voffA0 = row * 256 + (((kg ^ row) & 7) << 4);                       // h k0..31
    const int voffA2 = rowR * 256 + (((kg ^ rowR) & 7) << 4) + (isT ? 128 : 0);   // agg k0..31
    int voffC[4];
    #pragma unroll
    for (int r = 0; r < 4; ++r) {
        const int rr = (kg << 2) + r;          // C/D row = (lane>>4)*4 + r
        voffC[r] = rr * 256 + (((((ct << 1) + ((lane >> 3) & 1)) ^ rr) & 7) << 4) + ((lane & 7) << 1);
    }

    // --- encoder: wave ct -> graph ct, rows fully unrolled ---
    float ewt[8], ewl[4];
    #pragma unroll
    for (int k = 0; k < 8; ++k) ewt[k] = Wt[(k << 6) + lane];
    #pragma unroll
    for (int k = 0; k < 4; ++k) ewl[k] = Wl[(k << 6) + lane];
    const float ebt = bt[lane], ebl = bl[lane];

    const float4* xg = (const float4*)(x + (size_t)(g0 + ct) * 120);
    #pragma unroll
    for (int p = 0; p < 15; ++p) {
        const float4 a0 = xg[p * 2];
        float acc;
        if (p % 3 == 0) {
            const float4 a1 = xg[p * 2 + 1];
            acc = ebt + a0.x * ewt[0] + a0.y * ewt[1] + a0.z * ewt[2] + a0.w * ewt[3]
                      + a1.x * ewt[4] + a1.y * ewt[5] + a1.z * ewt[6] + a1.w * ewt[7];
        } else {
            acc = ebl + a0.x * ewl[0] + a0.y * ewl[1] + a0.z * ewl[2] + a0.w * ewl[3];
        }
        *(unsigned short*)(smem + wbase + p * 256 + (colb ^ ((p & 7) << 4))) =
            (unsigned short)f2bfu(fast_tanh(acc));
    }
    // zero pad row 15 (h + agg halves) for determinism
    *(unsigned short*)(smem + wbase + 15 * 256 + (colb ^ 0x70)) = 0;
    *(unsigned short*)(smem + wbase + 15 * 256 + 128 + (colb ^ 0x70)) = 0;

    AGG();                   // same wave, same lane as encoder writes -> no barrier before
    __syncthreads();

    // --- 3x GraphConv via MFMA; wave ct = col-tile ct for all 4 graphs ---
    #pragma unroll
    for (int it = 0; it < 3; ++it) {
        const float cbi = (it == 0) ? cb0 : (it == 1) ? cb1 : cb2;
        f32x4 acc[GPB];
        #pragma unroll
        for (int g = 0; g < GPB; ++g) {
            const unsigned char* sg = smem + g * 4096;
            const bf16x8 a0 = *(const bf16x8*)(sg + voffA0);
            const bf16x8 a1 = *(const bf16x8*)(sg + (voffA0 ^ 0x40));
            const bf16x8 a2 = *(const bf16x8*)(sg + voffA2);
            const bf16x8 a3 = *(const bf16x8*)(sg + (voffA2 ^ 0x40));
            f32x4 c = { cbi, cbi, cbi, cbi };
            c = __builtin_amdgcn_mfma_f32_16x16x32_bf16(a0, bfr[it][0], c, 0, 0, 0);
            c = __builtin_amdgcn_mfma_f32_16x16x32_bf16(a1, bfr[it][1], c, 0, 0, 0);
            c = __builtin_amdgcn_mfma_f32_16x16x32_bf16(a2, bfr[it][2], c, 0, 0, 0);
            c = __builtin_amdgcn_mfma_f32_16x16x32_bf16(a3, bfr[it][3], c, 0, 0, 0);
            acc[g] = c;
        }
        __syncthreads();     // all A reads done before overwriting h
        #pragma unroll
        for (int g = 0; g < GPB; ++g)
            #pragma unroll
            for (int r = 0; r < 4; ++r)
                *(unsigned short*)(smem + g * 4096 + voffC[r]) =
                    (unsigned short)f2bfu(fast_tanh(acc[g][r]));
        __syncthreads();
        if (it < 2) { AGG(); __syncthreads(); }
    }

    // --- heads: wave ct -> graph ct, lane = (p,j) item ---
    if (lane < 56) {
        const int p = (lane >> 2) + 1, j = lane & 3;
        const int p3 = (p * 11) >> 5;
        const int pm3 = p - p3 * 3;
        float bias;
        if (pm3 == 0) bias = torB[((p3 - 1) << 2) + j];
        else          bias = legB[(((p3 << 1) + pm3 - 1) << 2) + j];
        const unsigned* wp = wsw + 12288 + (lane << 5);        // item*8 dwordx4 -> *32 dwords
        const unsigned char* hb = smem + wbase + p * 256;
        const int ps = (p & 7) << 4;
        float acc = 0.f;
        #pragma unroll
        for (int k8 = 0; k8 < 8; ++k8) {
            const u32x4 hv = *(const u32x4*)(hb + (ps ^ (k8 << 4)));
            const u32x4 wv = *(const u32x4*)(wp + (k8 << 2));
            #pragma unroll
            for (int dd = 0; dd < 4; ++dd) {
                acc = __builtin_fmaf(lof(hv[dd]), lof(wv[dd]), acc);
                acc = __builtin_fmaf(hif(hv[dd]), hif(wv[dd]), acc);
            }
        }
        acc += bias;
        const int mloc = ((p - 1) << 1) + (j >> 1);
        const size_t ob = (size_t)(g0 + ct) * 28 + mloc;
        if ((j & 1) == 0) {
            out[ob] = acc;
        } else {
            const float z = acc + BIAS_SP;
            const float sp = (z > 15.f) ? z : __logf(1.f + __expf(z));
            out[(size_t)NB * 28 + ob] = fmaxf(sp, 1e-4f);
        }
    }
}

extern "C" void kernel_launch(void* const* d_in, const int* in_sizes, int n_in,
                              void* d_out, int out_size, void* d_ws, size_t ws_size,
                              hipStream_t stream) {
    (void)in_sizes; (void)n_in; (void)out_size; (void)ws_size;
    const float* x     = (const float*)d_in[0];
    // d_in[1] = edge_index (fixed template, unused), d_in[2] = batch_size
    const float* Wt    = (const float*)d_in[3];
    const float* bt    = (const float*)d_in[4];
    const float* Wl    = (const float*)d_in[5];
    const float* bl    = (const float*)d_in[6];
    const float* Wroot = (const float*)d_in[7];
    const float* Wrel  = (const float*)d_in[8];
    const float* gcb   = (const float*)d_in[9];
    const float* legW  = (const float*)d_in[10];
    const float* legB  = (const float*)d_in[11];
    const float* torW  = (const float*)d_in[12];
    const float* torB  = (const float*)d_in[13];
    unsigned* wsw = (unsigned*)d_ws;           // needs 56320 B of scratch
    setup_kernel<<<14, 256, 0, stream>>>(Wroot, Wrel, legW, torW, wsw);
    leg_main<<<NB / GPB, 256, 0, stream>>>(x, Wt, bt, Wl, bl, gcb, legB, torB, wsw,
                                           (float*)d_out);
}

// Round 5
// 79.035 us; speedup vs baseline: 2.8754x; 1.0497x over previous
//
#include <hip/hip_runtime.h>

#define NB 32768
#define GPB 8
#define THREADS 256
#define BIAS_SP 0.5413248546129181f

typedef __attribute__((ext_vector_type(8))) short bf16x8;
typedef __attribute__((ext_vector_type(4))) float f32x4;
typedef __attribute__((ext_vector_type(4))) unsigned int u32x4;

static __device__ __forceinline__ unsigned f2bfu(float f) {
    union { float f; unsigned u; } v; v.f = f;
    return (v.u + 0x8000u) >> 16;
}
static __device__ __forceinline__ unsigned f2bfu_hi(float f) {
    union { float f; unsigned u; } v; v.f = f;
    return (v.u + 0x8000u) & 0xFFFF0000u;
}
static __device__ __forceinline__ float lof(unsigned u) {
    union { unsigned u; float f; } v; v.u = u << 16; return v.f;
}
static __device__ __forceinline__ float hif(unsigned u) {
    union { unsigned u; float f; } v; v.u = u & 0xFFFF0000u; return v.f;
}
static __device__ __forceinline__ float fast_tanh(float xx) {
    float e = __expf(2.0f * xx);
    return 1.0f - 2.0f * __builtin_amdgcn_rcpf(e + 1.0f);
}

// ---------------------------------------------------------------------------
// Setup: pack conv B-fragments (bf16, MFMA lane order) and head weights
// (bf16 [item=(p-1)*4+j][k=0..63]) into the workspace.
// ws layout (dwords): [0,12288) conv B-frags, [12288,14080) head weights.
// ---------------------------------------------------------------------------
__global__ void setup_kernel(const float* __restrict__ Wroot, const float* __restrict__ Wrel,
                             const float* __restrict__ legW, const float* __restrict__ torW,
                             unsigned* __restrict__ wsw) {
    const int t = blockIdx.x * 256 + threadIdx.x;
    if (t < 3072) {                       // (i,s,ct,lane) B-fragment element pack
        const int i = t >> 10, rem = t & 1023, s = rem >> 8, tt = rem & 255;
        const int lane = tt & 63, ctl = tt >> 6;
        const int bcol = (ctl << 4) + (lane & 15);
        const int kb = ((s & 1) << 5) + ((lane >> 4) << 3);
        const float* M = ((s < 2) ? Wroot : Wrel) + i * 4096 + kb * 64 + bcol;
        u32x4 d;
        #pragma unroll
        for (int dd = 0; dd < 4; ++dd)
            d[dd] = f2bfu(M[(2 * dd) * 64]) | (f2bfu(M[(2 * dd + 1) * 64]) << 16);
        *(u32x4*)(wsw + t * 4) = d;
    } else if (t < 3520) {                // head weights
        const int t2 = t - 3072, item = t2 >> 3, k8 = t2 & 7;
        const int p = (item >> 2) + 1, j = item & 3;
        const int p3 = (p * 11) >> 5;     // p/3 for p<16
        const int pm3 = p - p3 * 3;
        const float* src;
        if (pm3 == 0) src = torW + (p3 - 1) * 256 + j;
        else          src = legW + (2 * p3 + pm3 - 1) * 256 + j;
        u32x4 d;
        #pragma unroll
        for (int dd = 0; dd < 4; ++dd) {
            const int k = (k8 << 3) + 2 * dd;
            d[dd] = f2bfu(src[k * 4]) | (f2bfu(src[(k + 1) * 4]) << 16);
        }
        *(u32x4*)(wsw + 12288 + t2 * 4) = d;
    }
}

// ---------------------------------------------------------------------------
// Main: 8 graphs/block, 4 waves. Conv: wave = col-tile (16 cols), all 8 graphs.
// Enc/AGG/heads: wave owns graphs 2*ct, 2*ct+1.
// LDS/graph: 16 rows x 16 slots(16B) = 4KB; slots 0-7 = h, 8-15 = agg.
// Swizzle: slot_low3 ^= (row & 7) -> row-strided access conflict-free.
// ---------------------------------------------------------------------------
__global__ __launch_bounds__(THREADS, 5) void leg_main(
    const float* __restrict__ x,
    const float* __restrict__ Wt, const float* __restrict__ bt,
    const float* __restrict__ Wl, const float* __restrict__ bl,
    const float* __restrict__ gcb,
    const float* __restrict__ legB, const float* __restrict__ torB,
    const unsigned* __restrict__ wsw,
    float* __restrict__ out)
{
    __shared__ __align__(16) unsigned char smem[GPB * 4096];
    const int tid  = threadIdx.x;
    const int lane = tid & 63;
    const int ct   = tid >> 6;                 // wave id
    const int g0   = blockIdx.x * GPB;

    const int bcol = (ct << 4) + (lane & 15);
    const float cb0 = gcb[bcol], cb1 = gcb[64 + bcol], cb2 = gcb[128 + bcol];

    // --- per-lane LDS byte offsets (conv) ---
    const int colb = ((lane >> 3) << 4) + ((lane & 7) << 1);   // col = lane (u16)
    const int row = lane & 15, kg = lane >> 4;
    const int row3 = (row * 11) >> 5;
    const int tors = row3 * 3;
    const int isT  = (row == tors);
    const int rowR = isT ? row : tors;         // leg rows read torso h as their agg
    const int voffA0 = row * 256 + (((kg ^ row) & 7) << 4);
    const int voffA2 = rowR * 256 + (((kg ^ rowR) & 7) << 4) + (isT ? 128 : 0);
    int voffC[4];
    #pragma unroll
    for (int r = 0; r < 4; ++r) {
        const int rr = (kg << 2) + r;
        voffC[r] = rr * 256 + (((((ct << 1) + ((lane >> 3) & 1)) ^ rr) & 7) << 4) + ((lane & 7) << 1);
    }

    // --- paired-AGG lane mapping: lanes<32 -> graph 2ct, >=32 -> 2ct+1 ---
    const int half = lane >> 5;
    const int c2   = lane & 31;                // dword index within 64-col row
    unsigned char* gbase = smem + ((ct << 1) + half) * 4096;
    const int aoff = (c2 & 3) << 2;
#define RD32(r)  (*(const unsigned*)(gbase + (r) * 256 + (((((c2) >> 2) ^ (r)) & 7) << 4) + aoff))
#define WR32(r, flo, fhi) *(unsigned*)(gbase + (r) * 256 + 128 + (((((c2) >> 2) ^ (r)) & 7) << 4) + aoff) = (f2bfu(flo) | f2bfu_hi(fhi))
#define AGG() do { \
    unsigned u[15]; \
    _Pragma("unroll") for (int r = 0; r < 15; ++r) u[r] = RD32(r); \
    float l3 = lof(u[3]), h3 = hif(u[3]), l6 = lof(u[6]), h6 = hif(u[6]), l9 = lof(u[9]), h9 = hif(u[9]); \
    WR32(0,  lof(u[1]) + lof(u[2]) + l3,              hif(u[1]) + hif(u[2]) + h3); \
    WR32(3,  lof(u[4]) + lof(u[5]) + lof(u[0]) + l6,  hif(u[4]) + hif(u[5]) + hif(u[0]) + h6); \
    WR32(6,  lof(u[7]) + lof(u[8]) + l3 + l9,         hif(u[7]) + hif(u[8]) + h3 + h9); \
    WR32(9,  lof(u[10]) + lof(u[11]) + l6 + lof(u[12]), hif(u[10]) + hif(u[11]) + h6 + hif(u[12])); \
    WR32(12, lof(u[13]) + lof(u[14]) + l9,            hif(u[13]) + hif(u[14]) + h9); \
} while (0)

    // --- encoder: wave ct -> graphs 2ct, 2ct+1 ---
    float ewt[8], ewl[4];
    #pragma unroll
    for (int k = 0; k < 8; ++k) ewt[k] = Wt[(k << 6) + lane];
    #pragma unroll
    for (int k = 0; k < 4; ++k) ewl[k] = Wl[(k << 6) + lane];
    const float ebt = bt[lane], ebl = bl[lane];

    #pragma unroll
    for (int gs = 0; gs < 2; ++gs) {
        const int g = (ct << 1) + gs;
        const float4* xg = (const float4*)(x + (size_t)(g0 + g) * 120);
        unsigned char* sb = smem + g * 4096;
        #pragma unroll
        for (int p = 0; p < 15; ++p) {
            const float4 a0 = xg[p * 2];
            float acc;
            if (p % 3 == 0) {
                const float4 a1 = xg[p * 2 + 1];
                acc = ebt + a0.x * ewt[0] + a0.y * ewt[1] + a0.z * ewt[2] + a0.w * ewt[3]
                          + a1.x * ewt[4] + a1.y * ewt[5] + a1.z * ewt[6] + a1.w * ewt[7];
            } else {
                acc = ebl + a0.x * ewl[0] + a0.y * ewl[1] + a0.z * ewl[2] + a0.w * ewl[3];
            }
            *(unsigned short*)(sb + p * 256 + (colb ^ ((p & 7) << 4))) =
                (unsigned short)f2bfu(fast_tanh(acc));
        }
        *(unsigned short*)(sb + 15 * 256 + (colb ^ 0x70)) = 0;          // pad row h
        *(unsigned short*)(sb + 15 * 256 + 128 + (colb ^ 0x70)) = 0;    // pad row agg
    }
    // Paired AGG reads cols written by OTHER lanes -> barrier required.
    __syncthreads();
    AGG();
    __syncthreads();

    // --- 3x GraphConv via MFMA; wave ct = col-tile for all 8 graphs ---
    #pragma unroll
    for (int it = 0; it < 3; ++it) {
        bf16x8 bfr[4];
        #pragma unroll
        for (int s = 0; s < 4; ++s)
            bfr[s] = *(const bf16x8*)(wsw + ((it * 4 + s) * 256 + tid) * 4);
        const float cbi = (it == 0) ? cb0 : (it == 1) ? cb1 : cb2;
        f32x4 acc[GPB];
        #pragma unroll
        for (int g = 0; g < GPB; ++g) {
            const unsigned char* sg = smem + g * 4096;
            const bf16x8 a0 = *(const bf16x8*)(sg + voffA0);
            const bf16x8 a1 = *(const bf16x8*)(sg + (voffA0 ^ 0x40));
            const bf16x8 a2 = *(const bf16x8*)(sg + voffA2);
            const bf16x8 a3 = *(const bf16x8*)(sg + (voffA2 ^ 0x40));
            f32x4 c = { cbi, cbi, cbi, cbi };
            c = __builtin_amdgcn_mfma_f32_16x16x32_bf16(a0, bfr[0], c, 0, 0, 0);
            c = __builtin_amdgcn_mfma_f32_16x16x32_bf16(a1, bfr[1], c, 0, 0, 0);
            c = __builtin_amdgcn_mfma_f32_16x16x32_bf16(a2, bfr[2], c, 0, 0, 0);
            c = __builtin_amdgcn_mfma_f32_16x16x32_bf16(a3, bfr[3], c, 0, 0, 0);
            acc[g] = c;
        }
        __syncthreads();     // all A reads done before overwriting h
        #pragma unroll
        for (int g = 0; g < GPB; ++g)
            #pragma unroll
            for (int r = 0; r < 4; ++r)
                *(unsigned short*)(smem + g * 4096 + voffC[r]) =
                    (unsigned short)f2bfu(fast_tanh(acc[g][r]));
        __syncthreads();
        if (it < 2) { AGG(); __syncthreads(); }
    }

    // --- heads: wave ct -> graphs 2ct, 2ct+1; lane = (p,j) item ---
    // NOTE: unpack-FMA path (proven round 2). Raw-asm v_dot2_f32_bf16 gave a
    // deterministic 4.7e-2 error (VOP3P op_sel_hi default suspect) - reverted.
    if (lane < 56) {
        const int p = (lane >> 2) + 1, j = lane & 3;
        const int p3 = (p * 11) >> 5;
        const int pm3 = p - p3 * 3;
        float bias;
        if (pm3 == 0) bias = torB[((p3 - 1) << 2) + j];
        else          bias = legB[(((p3 << 1) + pm3 - 1) << 2) + j];
        const unsigned* wp = wsw + 12288 + (lane << 5);
        const int ps = (p & 7) << 4;
        #pragma unroll
        for (int gs = 0; gs < 2; ++gs) {
            const int g = (ct << 1) + gs;
            const unsigned char* hb = smem + g * 4096 + p * 256;
            float acc = 0.f;
            #pragma unroll
            for (int k8 = 0; k8 < 8; ++k8) {
                const u32x4 hv = *(const u32x4*)(hb + (ps ^ (k8 << 4)));
                const u32x4 wv = *(const u32x4*)(wp + (k8 << 2));
                #pragma unroll
                for (int dd = 0; dd < 4; ++dd) {
                    acc = __builtin_fmaf(lof(hv[dd]), lof(wv[dd]), acc);
                    acc = __builtin_fmaf(hif(hv[dd]), hif(wv[dd]), acc);
                }
            }
            acc += bias;
            const int mloc = ((p - 1) << 1) + (j >> 1);
            const size_t ob = (size_t)(g0 + g) * 28 + mloc;
            if ((j & 1) == 0) {
                out[ob] = acc;
            } else {
                const float z = acc + BIAS_SP;
                const float sp = (z > 15.f) ? z : __logf(1.f + __expf(z));
                out[(size_t)NB * 28 + ob] = fmaxf(sp, 1e-4f);
            }
        }
    }
}

extern "C" void kernel_launch(void* const* d_in, const int* in_sizes, int n_in,
                              void* d_out, int out_size, void* d_ws, size_t ws_size,
                              hipStream_t stream) {
    (void)in_sizes; (void)n_in; (void)out_size; (void)ws_size;
    const float* x     = (const float*)d_in[0];
    // d_in[1] = edge_index (fixed template, unused), d_in[2] = batch_size
    const float* Wt    = (const float*)d_in[3];
    const float* bt    = (const float*)d_in[4];
    const float* Wl    = (const float*)d_in[5];
    const float* bl    = (const float*)d_in[6];
    const float* Wroot = (const float*)d_in[7];
    const float* Wrel  = (const float*)d_in[8];
    const float* gcb   = (const float*)d_in[9];
    const float* legW  = (const float*)d_in[10];
    const float* legB  = (const float*)d_in[11];
    const float* torW  = (const float*)d_in[12];
    const float* torB  = (const float*)d_in[13];
    unsigned* wsw = (unsigned*)d_ws;           // needs 56320 B of scratch
    setup_kernel<<<14, 256, 0, stream>>>(Wroot, Wrel, legW, torW, wsw);
    leg_main<<<NB / GPB, 256, 0, stream>>>(x, Wt, bt, Wl, bl, gcb, legB, torB, wsw,
                                           (float*)d_out);
}